// Round 1
// baseline (252.268 us; speedup 1.0000x reference)
//
#include <hip/hip_runtime.h>
#include <cmath>

typedef __bf16 bf16_t;
typedef bf16_t bf16x8 __attribute__((ext_vector_type(8)));
typedef bf16_t bf16x4 __attribute__((ext_vector_type(4)));
typedef float  f32x4  __attribute__((ext_vector_type(4)));

#define Bn  4
#define TQn 1024
#define TKn 1024
#define En  1024
#define Hn  16
#define DHn 64

static constexpr float EPSv = 1e-5f;
// softmax in exp2 domain: scale = (1/sqrt(64)) * log2(e)
static constexpr float C_SCALE = 0.18033688011112042f;

#define GLDS16(g, l)                                                         \
    __builtin_amdgcn_global_load_lds(                                        \
        (const __attribute__((address_space(1))) void*)(g),                  \
        (__attribute__((address_space(3))) void*)(l), 16, 0, 0)

// ---------------------------------------------------------------------------
// fp32 -> bf16 conversion, all tensors fused. (No stats zeroing needed any
// more: GN stats are plain per-block stores now, not atomics.)
// ---------------------------------------------------------------------------
__global__ __launch_bounds__(256)
void cvt_all(const float* __restrict__ x, const float* __restrict__ enc,
             const float* __restrict__ q1w, const float* __restrict__ q2w,
             const float* __restrict__ k1w, const float* __restrict__ k2w,
             const float* __restrict__ vw,  const float* __restrict__ outw,
             bf16_t* __restrict__ xb, bf16_t* __restrict__ encb,
             bf16_t* __restrict__ wq, bf16_t* __restrict__ wkv,
             bf16_t* __restrict__ wob)
{
    int idx = blockIdx.x * 256 + threadIdx.x;   // 0 .. 3670015
    const float* src; bf16_t* dst;
    if      (idx < 1048576) { src = x    + (size_t)idx * 4;              dst = xb   + (size_t)idx * 4; }
    else if (idx < 2097152) { src = enc  + (size_t)(idx - 1048576) * 4;  dst = encb + (size_t)(idx - 1048576) * 4; }
    else if (idx < 2359296) { src = q1w  + (size_t)(idx - 2097152) * 4;  dst = wq   + (size_t)(idx - 2097152) * 4; }
    else if (idx < 2621440) { src = q2w  + (size_t)(idx - 2359296) * 4;  dst = wq   + 1048576 + (size_t)(idx - 2359296) * 4; }
    else if (idx < 2883584) { src = k1w  + (size_t)(idx - 2621440) * 4;  dst = wkv  + (size_t)(idx - 2621440) * 4; }
    else if (idx < 3145728) { src = k2w  + (size_t)(idx - 2883584) * 4;  dst = wkv  + 1048576 + (size_t)(idx - 2883584) * 4; }
    else if (idx < 3407872) { src = vw   + (size_t)(idx - 3145728) * 4;  dst = wkv  + 2097152 + (size_t)(idx - 3145728) * 4; }
    else                    { src = outw + (size_t)(idx - 3407872) * 4;  dst = wob  + (size_t)(idx - 3407872) * 4; }
    float4 v = *(const float4*)src;
    bf16x4 o;
    o[0] = (bf16_t)v.x; o[1] = (bf16_t)v.y; o[2] = (bf16_t)v.z; o[3] = (bf16_t)v.w;
    *(bf16x4*)dst = o;
}

// ---------------------------------------------------------------------------
// MFMA GEMM core (m97 recipe): 128xBN tile, BK=64, GLDS16 staging w/ source
// swizzle, XOR-swizzled LDS, 4 waves 2x2, mfma_f32_16x16x32_bf16.
// C[m,n] = sum_k A[m,k] * W[n,k] + bias(n)
// OUTMODE 0: scatter bf16 to [seg,b,h,t,d]; OUTMODE 1: fp32 row-major [M,1024]
// BN=128 (NJ=4) or BN=64 (NJ=2, doubles grid for small-N gemms -> 2 blk/CU).
// ---------------------------------------------------------------------------
template<int OUTMODE, int BN>
__device__ __forceinline__
void gemm_core(const bf16_t* __restrict__ A, const bf16_t* __restrict__ W,
               const float* __restrict__ bp, void* __restrict__ Cout,
               int K, int blockM, int blockN,
               bf16_t* __restrict__ sA, bf16_t* __restrict__ sB)
{
    constexpr int NJ = BN / 32;     // acc tiles along N per wave
    constexpr int CB = BN / 32;     // 2048-elem staging chunks for B
    const int tid = threadIdx.x;
    const int w = tid >> 6, lane = tid & 63;
    const int q = lane >> 4, r = lane & 15;
    const int wm = w & 1, wn = w >> 1;

    f32x4 acc[4][NJ];
#pragma unroll
    for (int i = 0; i < 4; ++i)
#pragma unroll
        for (int j = 0; j < NJ; ++j) acc[i][j] = (f32x4){0.f, 0.f, 0.f, 0.f};

    for (int k0 = 0; k0 < K; k0 += 64) {
#pragma unroll
        for (int c = 0; c < 4; ++c) {
            const int s = c * 256 + tid;
            const int row = s >> 3;
            const int cg = (s & 7) ^ (row & 7);     // source-swizzle for GLDS
            GLDS16(A + (size_t)(blockM + row) * K + k0 + cg * 8, sA + c * 2048 + w * 512);
            if (c < CB)
                GLDS16(W + (size_t)(blockN + row) * K + k0 + cg * 8, sB + c * 2048 + w * 512);
        }
        __syncthreads();
#pragma unroll
        for (int ks = 0; ks < 2; ++ks) {
            bf16x8 a[4], b[NJ];
#pragma unroll
            for (int i = 0; i < 4; ++i) {
                const int row = wm * 64 + i * 16 + r;
                const int g = (ks * 4 + q) ^ (row & 7);
                a[i] = *(const bf16x8*)&sA[row * 64 + g * 8];
            }
#pragma unroll
            for (int j = 0; j < NJ; ++j) {
                const int row = wn * (BN / 2) + j * 16 + r;
                const int g = (ks * 4 + q) ^ (row & 7);
                b[j] = *(const bf16x8*)&sB[row * 64 + g * 8];
            }
#pragma unroll
            for (int i = 0; i < 4; ++i)
#pragma unroll
                for (int j = 0; j < NJ; ++j)
                    acc[i][j] = __builtin_amdgcn_mfma_f32_16x16x32_bf16(a[i], b[j], acc[i][j], 0, 0, 0);
        }
        __syncthreads();
    }

    const int seg = blockN >> 10;
#pragma unroll
    for (int j = 0; j < NJ; ++j) {
        const int n = blockN + wn * (BN / 2) + j * 16 + r;
        const float bv = bp[n & 1023];
#pragma unroll
        for (int i = 0; i < 4; ++i) {
            f32x4 v = acc[i][j];
#pragma unroll
            for (int e = 0; e < 4; ++e) {
                const int m = blockM + wm * 64 + i * 16 + q * 4 + e;
                const float val = v[e] + bv;
                if (OUTMODE == 0) {
                    const int bb = m >> 10, t = m & 1023;
                    const int h = (n >> 6) & 15, d = n & 63;
                    ((bf16_t*)Cout)[((((size_t)seg * 4 + bb) * 16 + h) * 1024 + t) * 64 + d] = (bf16_t)val;
                } else {
                    ((float*)Cout)[(size_t)m * 1024 + n] = val;
                }
            }
        }
    }
}

// Fused projection GEMM: grid x 0..15 -> q12 (N=2048), 16..39 -> k12v (N=3072).
// One launch instead of two: tails overlap, one less dispatch boundary.
__global__ __launch_bounds__(256, 3)
void gemm_proj(const bf16_t* __restrict__ xb, const bf16_t* __restrict__ encb,
               const bf16_t* __restrict__ wq, const bf16_t* __restrict__ wkv,
               const float* __restrict__ q1b, const float* __restrict__ q2b,
               const float* __restrict__ k1b, const float* __restrict__ k2b,
               const float* __restrict__ vb,
               bf16_t* __restrict__ q12, bf16_t* __restrict__ k12v)
{
    __shared__ bf16_t sA[128 * 64];
    __shared__ bf16_t sB[128 * 64];
    int bx = blockIdx.x;
    const bf16_t* A; const bf16_t* W; bf16_t* C; const float* bp; int blockN;
    if (bx < 16) {
        A = xb; W = wq; C = q12; blockN = bx << 7;
        bp = (blockN >> 10) ? q2b : q1b;
    } else {
        bx -= 16;
        A = encb; W = wkv; C = k12v; blockN = bx << 7;
        const int seg = blockN >> 10;
        bp = (seg == 0) ? k1b : ((seg == 1) ? k2b : vb);
    }
    gemm_core<0, 128>(A, W, bp, C, 1024, blockIdx.y << 7, blockN, sA, sB);
}

// Output GEMM: N=1024 only -> BN=64 tiles give grid 512 = 2 blocks/CU
// (128-wide tiles gave 256 blocks = 1/CU: no stage/compute overlap).
__global__ __launch_bounds__(256, 3)
void gemm_out(const bf16_t* __restrict__ yb, const bf16_t* __restrict__ wob,
              const float* __restrict__ outb, float* __restrict__ out)
{
    __shared__ bf16_t sA[128 * 64];
    __shared__ bf16_t sB[64 * 64];
    gemm_core<1, 64>(yb, wob, outb, out, 1024, blockIdx.y << 7, blockIdx.x << 6, sA, sB);
}

// ---------------------------------------------------------------------------
// Attention phase helpers (transposed-S structure, no running max)
// ---------------------------------------------------------------------------
__device__ __forceinline__ void compute_S(const bf16_t* __restrict__ sK,
                                          const bf16x8 (&fQ)[2][2],
                                          f32x4 (&S)[4][2], int q, int r)
{
#pragma unroll
    for (int i = 0; i < 4; ++i)
#pragma unroll
        for (int j = 0; j < 2; ++j) S[i][j] = (f32x4){0.f, 0.f, 0.f, 0.f};
#pragma unroll
    for (int ks = 0; ks < 2; ++ks) {
        bf16x8 fK[4];
#pragma unroll
        for (int i = 0; i < 4; ++i) {
            const int row = i * 16 + r;
            const int g = (ks * 4 + q) ^ (row & 7);
            fK[i] = *(const bf16x8*)&sK[row * 64 + g * 8];
        }
        __builtin_amdgcn_s_setprio(1);
#pragma unroll
        for (int i = 0; i < 4; ++i)
#pragma unroll
            for (int j = 0; j < 2; ++j)
                S[i][j] = __builtin_amdgcn_mfma_f32_16x16x32_bf16(fK[i], fQ[j][ks], S[i][j], 0, 0, 0);
        __builtin_amdgcn_s_setprio(0);
    }
}

__device__ __forceinline__ void softmax_pw(f32x4 (&S)[4][2], bf16_t* __restrict__ sPt,
                                           float (&l)[2], int w, int q, int r)
{
#pragma unroll
    for (int j = 0; j < 2; ++j) {
        const int t = w * 32 + j * 16 + r;
        float part = 0.f;
#pragma unroll
        for (int i = 0; i < 4; ++i) {
            bf16x4 pk;
#pragma unroll
            for (int e = 0; e < 4; ++e) {
                const float p = __builtin_amdgcn_exp2f(S[i][j][e] * C_SCALE);
                part += p;
                pk[e] = (bf16_t)p;
            }
            const int sb = i * 16 + q * 4;
            const int g = (sb >> 3) ^ (t & 7);
            *(bf16x4*)&sPt[t * 64 + g * 8 + (sb & 7)] = pk;
        }
        l[j] += part;
    }
}

__device__ __forceinline__ void pv(const bf16_t* __restrict__ sPt,
                                   const bf16x8 (&fV)[4][2],
                                   f32x4 (&O)[2][4], int w, int q, int r)
{
#pragma unroll
    for (int ks = 0; ks < 2; ++ks) {
        bf16x8 fP[2];
#pragma unroll
        for (int i2 = 0; i2 < 2; ++i2) {
            const int m = w * 32 + i2 * 16 + r;
            const int g = (ks * 4 + q) ^ (m & 7);
            fP[i2] = *(const bf16x8*)&sPt[m * 64 + g * 8];
        }
        __builtin_amdgcn_s_setprio(1);
#pragma unroll
        for (int i2 = 0; i2 < 2; ++i2)
#pragma unroll
            for (int j = 0; j < 4; ++j)
                O[i2][j] = __builtin_amdgcn_mfma_f32_16x16x32_bf16(fP[i2], fV[j][ks], O[i2][j], 0, 0, 0);
        __builtin_amdgcn_s_setprio(0);
    }
}

// ---------------------------------------------------------------------------
// Differential flash attention, bf16 MFMA, transposed-S, dbuf-K, XCD-local.
// Grid dim3(64, 8): x = bh (keeps all 8 q-blocks of a bh on one XCD -> K/V
// stay L2-resident), y = qt. Block 256 thr, Q-tile 128 rows, K-tile 64.
// GN partials: plain per-(bh,qt) stores (no atomics, no zero-init contract).
// ---------------------------------------------------------------------------
__global__ __launch_bounds__(256, 2)
void diff_attn_mfma(const bf16_t* __restrict__ q12, const bf16_t* __restrict__ k12v,
                    const float* __restrict__ lam, bf16_t* __restrict__ out,
                    float* __restrict__ stats)
{
    __shared__ bf16_t sK1[2][64 * 64];
    __shared__ bf16_t sK2[2][64 * 64];
    __shared__ bf16_t sVt[64 * 64];     // [d][s], swizzled
    __shared__ bf16_t sPt1[128 * 64];   // [t][s], wave-private strips
    __shared__ bf16_t sPt2[128 * 64];
    __shared__ float  sl1[128], sl2[128];
    __shared__ float  sred[16];

    const int tid = threadIdx.x;
    const int w = tid >> 6, lane = tid & 63;
    const int q = lane >> 4, r = lane & 15;
    const int bh = blockIdx.x, qt = blockIdx.y;
    const float lamv = lam[bh & (Hn - 1)];

    const size_t HT = (size_t)TKn * DHn;          // 65536
    const bf16_t* q1g = q12 + (size_t)bh * HT + (size_t)qt * 128 * DHn;
    const bf16_t* q2g = q1g + 64 * HT;
    const bf16_t* k1g = k12v + (size_t)bh * HT;
    const bf16_t* k2g = k1g + 64 * HT;
    const bf16_t* vg  = k1g + 128 * HT;

    // Q fragments in registers (B-operand layout)
    bf16x8 fQ1[2][2], fQ2[2][2];
#pragma unroll
    for (int j = 0; j < 2; ++j) {
        const int t = w * 32 + j * 16 + r;
#pragma unroll
        for (int ks = 0; ks < 2; ++ks) {
            fQ1[j][ks] = *(const bf16x8*)(q1g + (size_t)t * 64 + ks * 32 + q * 8);
            fQ2[j][ks] = *(const bf16x8*)(q2g + (size_t)t * 64 + ks * 32 + q * 8);
        }
    }

    f32x4 O1[2][4], O2[2][4];
    float l1[2] = {0.f, 0.f}, l2[2] = {0.f, 0.f};
#pragma unroll
    for (int i = 0; i < 2; ++i)
#pragma unroll
        for (int j = 0; j < 4; ++j) { O1[i][j] = (f32x4){0.f,0.f,0.f,0.f}; O2[i][j] = (f32x4){0.f,0.f,0.f,0.f}; }

    // ---- prologue: stage K[0] (buf 0) and V[0] ----
    {
#pragma unroll
        for (int c = 0; c < 2; ++c) {
            const int s = c * 256 + tid;
            const int row = s >> 3;
            const int cg = (s & 7) ^ (row & 7);
            GLDS16(k1g + row * 64 + cg * 8, &sK1[0][c * 2048 + w * 512]);
            GLDS16(k2g + row * 64 + cg * 8, &sK2[0][c * 2048 + w * 512]);
        }
        bf16x8 v0[2];
#pragma unroll
        for (int rep = 0; rep < 2; ++rep)
            v0[rep] = *(const bf16x8*)(vg + (size_t)lane * 64 + (w * 2 + rep) * 8);
        __syncthreads();   // K[0] in LDS, v0 loaded
#pragma unroll
        for (int rep = 0; rep < 2; ++rep) {
            const int d0 = (w * 2 + rep) * 8;
#pragma unroll
            for (int i = 0; i < 8; ++i) {
                const int d = d0 + i;
                sVt[d * 64 + (((lane >> 3) ^ i) << 3) + (lane & 7)] = v0[rep][i];
            }
        }
        __syncthreads();   // sVt visible
    }

    bf16x8 vr[2];
    for (int st = 0; st < TKn / 64; ++st) {
        const int cur = st & 1;
        // ---- prefetch next tile: K via GLDS dbuf, V into registers ----
        if (st < 15) {
            const bf16_t* k1p = k1g + (size_t)(st + 1) * 4096;
            const bf16_t* k2p = k2g + (size_t)(st + 1) * 4096;
#pragma unroll
            for (int c = 0; c < 2; ++c) {
                const int s = c * 256 + tid;
                const int row = s >> 3;
                const int cg = (s & 7) ^ (row & 7);
                GLDS16(k1p + row * 64 + cg * 8, &sK1[cur ^ 1][c * 2048 + w * 512]);
                GLDS16(k2p + row * 64 + cg * 8, &sK2[cur ^ 1][c * 2048 + w * 512]);
            }
            const bf16_t* vp = vg + (size_t)(st + 1) * 4096;
#pragma unroll
            for (int rep = 0; rep < 2; ++rep)
                vr[rep] = *(const bf16x8*)(vp + (size_t)lane * 64 + (w * 2 + rep) * 8);
        }

        // ---- compute on current tile ----
        {
            f32x4 S[4][2];
            compute_S(sK1[cur], fQ1, S, q, r);
            softmax_pw(S, sPt1, l1, w, q, r);
        }
        {
            f32x4 S[4][2];
            compute_S(sK2[cur], fQ2, S, q, r);
            softmax_pw(S, sPt2, l2, w, q, r);
        }
        bf16x8 fV[4][2];
#pragma unroll
        for (int j = 0; j < 4; ++j)
#pragma unroll
            for (int ks = 0; ks < 2; ++ks) {
                const int d = j * 16 + r;
                const int g = (ks * 4 + q) ^ (d & 7);
                fV[j][ks] = *(const bf16x8*)&sVt[d * 64 + g * 8];
            }
        pv(sPt1, fV, O1, w, q, r);
        pv(sPt2, fV, O2, w, q, r);

        __syncthreads();   // all waves done with sVt & sK[cur]; prefetches drained
        if (st < 15) {
#pragma unroll
            for (int rep = 0; rep < 2; ++rep) {
                const int d0 = (w * 2 + rep) * 8;
#pragma unroll
                for (int i = 0; i < 8; ++i) {
                    const int d = d0 + i;
                    sVt[d * 64 + (((lane >> 3) ^ i) << 3) + (lane & 7)] = vr[rep][i];
                }
            }
            __syncthreads();   // sVt[st+1] visible
        }
    }

    // ---- l reduction across q-groups ----
#pragma unroll
    for (int j = 0; j < 2; ++j) {
        float v1 = l1[j];
        v1 += __shfl_xor(v1, 16); v1 += __shfl_xor(v1, 32);
        float v2 = l2[j];
        v2 += __shfl_xor(v2, 16); v2 += __shfl_xor(v2, 32);
        if (q == 0) { sl1[w * 32 + j * 16 + r] = v1; sl2[w * 32 + j * 16 + r] = v2; }
    }

    // ---- epilogue: out (bf16) + GN partial sums ----
    bf16_t* op = out + ((size_t)bh * TQn + (size_t)qt * 128) * DHn;
    float ssum = 0.f, ssq = 0.f;
#pragma unroll
    for (int i2 = 0; i2 < 2; ++i2)
#pragma unroll
        for (int e = 0; e < 4; ++e) {
            const int t = w * 32 + i2 * 16 + q * 4 + e;
            const float inv1 = 1.0f / sl1[t];
            const float inv2 = lamv / sl2[t];
#pragma unroll
            for (int j = 0; j < 4; ++j) {
                const float o = O1[i2][j][e] * inv1 - O2[i2][j][e] * inv2;
                op[(size_t)t * 64 + j * 16 + r] = (bf16_t)o;
                ssum += o;
                ssq += o * o;
            }
        }
#pragma unroll
    for (int d = 1; d < 64; d <<= 1) {
        ssum += __shfl_xor(ssum, d);
        ssq  += __shfl_xor(ssq, d);
    }
    if (lane == 0) { sred[w] = ssum; sred[8 + w] = ssq; }
    __syncthreads();
    if (tid == 0) {
        stats[(bh << 3) + qt]       = sred[0] + sred[1] + sred[2] + sred[3];
        stats[512 + (bh << 3) + qt] = sred[8] + sred[9] + sred[10] + sred[11];
    }
}

// ---------------------------------------------------------------------------
// GroupNorm apply (mu/rstd from per-(bh,qt) partials) + transpose -> y bf16
// ---------------------------------------------------------------------------
__global__ __launch_bounds__(256)
void gn_apply(const bf16_t* __restrict__ attn, const float* __restrict__ stats,
              const float* __restrict__ gamma, const float* __restrict__ beta,
              bf16_t* __restrict__ y)
{
    const int f = blockIdx.x * 256 + threadIdx.x;   // 8-elem group, 0..524287
    const int d8 = (f & 7) << 3;
    const int t  = (f >> 3) & 1023;
    const int bh = f >> 13;
    const int h  = bh & 15;
    const int b  = bh >> 4;
    const float* p1 = stats + (bh << 3);
    const float* p2 = stats + 512 + (bh << 3);
    float s1 = 0.f, s2 = 0.f;
#pragma unroll
    for (int k = 0; k < 8; ++k) { s1 += p1[k]; s2 += p2[k]; }
    const float mu = s1 * (1.f / 65536.f);
    const float var = s2 * (1.f / 65536.f) - mu * mu;
    const float rstd = rsqrtf(var + EPSv);
    bf16x8 v = *(const bf16x8*)&attn[((size_t)bh << 16) + t * 64 + d8];
    const int c = h * 64 + d8;
    const float* gp = gamma + c;
    const float* bp = beta + c;
    bf16x8 o;
#pragma unroll
    for (int i = 0; i < 8; ++i)
        o[i] = (bf16_t)(((float)v[i] - mu) * rstd * gp[i] + bp[i]);
    *(bf16x8*)&y[((size_t)(b * 1024 + t)) * 1024 + c] = o;
}

// ---------------------------------------------------------------------------
extern "C" void kernel_launch(void* const* d_in, const int* in_sizes, int n_in,
                              void* d_out, int out_size, void* d_ws, size_t ws_size,
                              hipStream_t stream)
{
    const float* x    = (const float*)d_in[0];
    const float* enc  = (const float*)d_in[1];
    const float* Q1w  = (const float*)d_in[2];
    const float* Q1b  = (const float*)d_in[3];
    const float* Q2w  = (const float*)d_in[4];
    const float* Q2b  = (const float*)d_in[5];
    const float* K1w  = (const float*)d_in[6];
    const float* K1b  = (const float*)d_in[7];
    const float* K2w  = (const float*)d_in[8];
    const float* K2b  = (const float*)d_in[9];
    const float* Vw   = (const float*)d_in[10];
    const float* Vb   = (const float*)d_in[11];
    const float* lam  = (const float*)d_in[12];
    const float* gng  = (const float*)d_in[13];
    const float* gnb  = (const float*)d_in[14];
    const float* outw = (const float*)d_in[15];
    const float* outb = (const float*)d_in[16];
    float* out = (float*)d_out;

    // workspace layout (bf16 elems). Peak footprint 68 MB (was 88 MB):
    // attnb/yb/stats alias regions that are dead after the projection GEMM.
    bf16_t* xb   = (bf16_t*)d_ws;            // 4,194,304   live k1..k2
    bf16_t* encb = xb   + 4194304;           // 4,194,304   live k1..k2
    bf16_t* wq   = encb + 4194304;           // 2,097,152   live k1..k2  [Q1w|Q2w]
    bf16_t* wkv  = wq   + 2097152;           // 3,145,728   live k1..k2  [K1w|K2w|Vw]
    bf16_t* wob  = wkv  + 3145728;           // 1,048,576   live k1..k5
    bf16_t* q12  = wob  + 1048576;           // 8,388,608   live k2..k3  [2][B][H][T][D]
    bf16_t* k12v = q12  + 8388608;           // 12,582,912  live k2..k3  [3][B][H][T][D]
    bf16_t* attnb= xb;                       // alias: written k3, read k4 (xb dead)
    bf16_t* yb   = encb;                     // alias: written k4, read k5 (encb dead)
    float*  stats= (float*)wq;               // alias: 1024 fp32, written k3, read k4 (wq dead)

    cvt_all<<<14336, 256, 0, stream>>>(x, enc, Q1w, Q2w, K1w, K2w, Vw, outw,
                                       xb, encb, wq, wkv, wob);

    gemm_proj<<<dim3(40, 32), 256, 0, stream>>>(xb, encb, wq, wkv,
                                                Q1b, Q2b, K1b, K2b, Vb, q12, k12v);

    diff_attn_mfma<<<dim3(64, 8), 256, 0, stream>>>(q12, k12v, lam, attnb, stats);

    gn_apply<<<2048, 256, 0, stream>>>(attnb, stats, gng, gnb, yb);

    gemm_out<<<dim3(16, 32), 256, 0, stream>>>(yb, wob, outb, out);
}

// Round 2
// 251.230 us; speedup vs baseline: 1.0041x; 1.0041x over previous
//
#include <hip/hip_runtime.h>
#include <cmath>

typedef __bf16 bf16_t;
typedef bf16_t bf16x8 __attribute__((ext_vector_type(8)));
typedef bf16_t bf16x4 __attribute__((ext_vector_type(4)));
typedef float  f32x4  __attribute__((ext_vector_type(4)));

#define Bn  4
#define TQn 1024
#define TKn 1024
#define En  1024
#define Hn  16
#define DHn 64

static constexpr float EPSv = 1e-5f;
// softmax in exp2 domain: scale = (1/sqrt(64)) * log2(e)
static constexpr float C_SCALE = 0.18033688011112042f;

#define GLDS16(g, l)                                                         \
    __builtin_amdgcn_global_load_lds(                                        \
        (const __attribute__((address_space(1))) void*)(g),                  \
        (__attribute__((address_space(3))) void*)(l), 16, 0, 0)

// ---------------------------------------------------------------------------
// fp32 -> bf16 conversion, all tensors fused.
// ---------------------------------------------------------------------------
__global__ __launch_bounds__(256)
void cvt_all(const float* __restrict__ x, const float* __restrict__ enc,
             const float* __restrict__ q1w, const float* __restrict__ q2w,
             const float* __restrict__ k1w, const float* __restrict__ k2w,
             const float* __restrict__ vw,  const float* __restrict__ outw,
             bf16_t* __restrict__ xb, bf16_t* __restrict__ encb,
             bf16_t* __restrict__ wq, bf16_t* __restrict__ wkv,
             bf16_t* __restrict__ wob)
{
    int idx = blockIdx.x * 256 + threadIdx.x;   // 0 .. 3670015
    const float* src; bf16_t* dst;
    if      (idx < 1048576) { src = x    + (size_t)idx * 4;              dst = xb   + (size_t)idx * 4; }
    else if (idx < 2097152) { src = enc  + (size_t)(idx - 1048576) * 4;  dst = encb + (size_t)(idx - 1048576) * 4; }
    else if (idx < 2359296) { src = q1w  + (size_t)(idx - 2097152) * 4;  dst = wq   + (size_t)(idx - 2097152) * 4; }
    else if (idx < 2621440) { src = q2w  + (size_t)(idx - 2359296) * 4;  dst = wq   + 1048576 + (size_t)(idx - 2359296) * 4; }
    else if (idx < 2883584) { src = k1w  + (size_t)(idx - 2621440) * 4;  dst = wkv  + (size_t)(idx - 2621440) * 4; }
    else if (idx < 3145728) { src = k2w  + (size_t)(idx - 2883584) * 4;  dst = wkv  + 1048576 + (size_t)(idx - 2883584) * 4; }
    else if (idx < 3407872) { src = vw   + (size_t)(idx - 3145728) * 4;  dst = wkv  + 2097152 + (size_t)(idx - 3145728) * 4; }
    else                    { src = outw + (size_t)(idx - 3407872) * 4;  dst = wob  + (size_t)(idx - 3407872) * 4; }
    float4 v = *(const float4*)src;
    bf16x4 o;
    o[0] = (bf16_t)v.x; o[1] = (bf16_t)v.y; o[2] = (bf16_t)v.z; o[3] = (bf16_t)v.w;
    *(bf16x4*)dst = o;
}

// ---------------------------------------------------------------------------
// Projection GEMM (m97 recipe, unchanged this round): 128x128 tile, BK=64.
// C[m,n] = sum_k A[m,k] * W[n,k] + bias(n); scatter bf16 to [seg,b,h,t,d].
// ---------------------------------------------------------------------------
__global__ __launch_bounds__(256, 3)
void gemm_proj(const bf16_t* __restrict__ xb, const bf16_t* __restrict__ encb,
               const bf16_t* __restrict__ wq, const bf16_t* __restrict__ wkv,
               const float* __restrict__ q1b, const float* __restrict__ q2b,
               const float* __restrict__ k1b, const float* __restrict__ k2b,
               const float* __restrict__ vb,
               bf16_t* __restrict__ q12, bf16_t* __restrict__ k12v)
{
    __shared__ bf16_t sA[128 * 64];
    __shared__ bf16_t sB[128 * 64];
    int bx = blockIdx.x;
    const bf16_t* A; const bf16_t* W; bf16_t* C; const float* bp; int blockN;
    if (bx < 16) {
        A = xb; W = wq; C = q12; blockN = bx << 7;
        bp = (blockN >> 10) ? q2b : q1b;
    } else {
        bx -= 16;
        A = encb; W = wkv; C = k12v; blockN = bx << 7;
        const int seg = blockN >> 10;
        bp = (seg == 0) ? k1b : ((seg == 1) ? k2b : vb);
    }
    const int blockM = blockIdx.y << 7;

    const int tid = threadIdx.x;
    const int w = tid >> 6, lane = tid & 63;
    const int q = lane >> 4, r = lane & 15;
    const int wm = w & 1, wn = w >> 1;

    f32x4 acc[4][4];
#pragma unroll
    for (int i = 0; i < 4; ++i)
#pragma unroll
        for (int j = 0; j < 4; ++j) acc[i][j] = (f32x4){0.f, 0.f, 0.f, 0.f};

    for (int k0 = 0; k0 < 1024; k0 += 64) {
#pragma unroll
        for (int c = 0; c < 4; ++c) {
            const int s = c * 256 + tid;
            const int row = s >> 3;
            const int cg = (s & 7) ^ (row & 7);
            GLDS16(A + (size_t)(blockM + row) * 1024 + k0 + cg * 8, sA + c * 2048 + w * 512);
            GLDS16(W + (size_t)(blockN + row) * 1024 + k0 + cg * 8, sB + c * 2048 + w * 512);
        }
        __syncthreads();
#pragma unroll
        for (int ks = 0; ks < 2; ++ks) {
            bf16x8 a[4], b[4];
#pragma unroll
            for (int i = 0; i < 4; ++i) {
                const int row = wm * 64 + i * 16 + r;
                const int g = (ks * 4 + q) ^ (row & 7);
                a[i] = *(const bf16x8*)&sA[row * 64 + g * 8];
            }
#pragma unroll
            for (int j = 0; j < 4; ++j) {
                const int row = wn * 64 + j * 16 + r;
                const int g = (ks * 4 + q) ^ (row & 7);
                b[j] = *(const bf16x8*)&sB[row * 64 + g * 8];
            }
#pragma unroll
            for (int i = 0; i < 4; ++i)
#pragma unroll
                for (int j = 0; j < 4; ++j)
                    acc[i][j] = __builtin_amdgcn_mfma_f32_16x16x32_bf16(a[i], b[j], acc[i][j], 0, 0, 0);
        }
        __syncthreads();
    }

    const int seg = blockN >> 10;
#pragma unroll
    for (int j = 0; j < 4; ++j) {
        const int n = blockN + wn * 64 + j * 16 + r;
        const float bv = bp[n & 1023];
#pragma unroll
        for (int i = 0; i < 4; ++i) {
            f32x4 v = acc[i][j];
#pragma unroll
            for (int e = 0; e < 4; ++e) {
                const int m = blockM + wm * 64 + i * 16 + q * 4 + e;
                const float val = v[e] + bv;
                const int bb = m >> 10, t = m & 1023;
                const int h = (n >> 6) & 15, d = n & 63;
                ((bf16_t*)C)[((((size_t)seg * 4 + bb) * 16 + h) * 1024 + t) * 64 + d] = (bf16_t)val;
            }
        }
    }
}

// ---------------------------------------------------------------------------
// Output GEMM: BM=64 x BN=128 tile + bijective XCD swizzle. Each XCD owns a
// contiguous 8-panel M-range (1 MB of A) -> A re-reads become XCD-L2 hits.
// 4 waves 1x4 (wave w owns n-range w*32..w*32+31), acc[4][2].
// ---------------------------------------------------------------------------
__global__ __launch_bounds__(256, 4)
void gemm_out(const bf16_t* __restrict__ yb, const bf16_t* __restrict__ wob,
              const float* __restrict__ outb, float* __restrict__ out)
{
    __shared__ bf16_t sA[64 * 64];
    __shared__ bf16_t sB[128 * 64];
    // flat grid 512: hw XCD = L%8; give each XCD y-chunk [xcd*8, xcd*8+8)
    const int L = blockIdx.x;
    const int xcd = L & 7, kk = L >> 3;
    const int blockM = (xcd * 8 + (kk >> 3)) * 64;
    const int blockN = (kk & 7) * 128;

    const int tid = threadIdx.x;
    const int w = tid >> 6, lane = tid & 63;
    const int q = lane >> 4, r = lane & 15;

    f32x4 acc[4][2];
#pragma unroll
    for (int i = 0; i < 4; ++i)
#pragma unroll
        for (int j = 0; j < 2; ++j) acc[i][j] = (f32x4){0.f, 0.f, 0.f, 0.f};

    for (int k0 = 0; k0 < 1024; k0 += 64) {
#pragma unroll
        for (int c = 0; c < 2; ++c) {
            const int s = c * 256 + tid;
            const int row = s >> 3;
            const int cg = (s & 7) ^ (row & 7);
            GLDS16(yb + (size_t)(blockM + row) * 1024 + k0 + cg * 8, sA + c * 2048 + w * 512);
        }
#pragma unroll
        for (int c = 0; c < 4; ++c) {
            const int s = c * 256 + tid;
            const int row = s >> 3;
            const int cg = (s & 7) ^ (row & 7);
            GLDS16(wob + (size_t)(blockN + row) * 1024 + k0 + cg * 8, sB + c * 2048 + w * 512);
        }
        __syncthreads();
#pragma unroll
        for (int ks = 0; ks < 2; ++ks) {
            bf16x8 a[4], b[2];
#pragma unroll
            for (int i = 0; i < 4; ++i) {
                const int row = i * 16 + r;
                const int g = (ks * 4 + q) ^ (row & 7);
                a[i] = *(const bf16x8*)&sA[row * 64 + g * 8];
            }
#pragma unroll
            for (int j = 0; j < 2; ++j) {
                const int row = w * 32 + j * 16 + r;
                const int g = (ks * 4 + q) ^ (row & 7);
                b[j] = *(const bf16x8*)&sB[row * 64 + g * 8];
            }
#pragma unroll
            for (int i = 0; i < 4; ++i)
#pragma unroll
                for (int j = 0; j < 2; ++j)
                    acc[i][j] = __builtin_amdgcn_mfma_f32_16x16x32_bf16(a[i], b[j], acc[i][j], 0, 0, 0);
        }
        __syncthreads();
    }

#pragma unroll
    for (int j = 0; j < 2; ++j) {
        const int n = blockN + w * 32 + j * 16 + r;
        const float bv = outb[n];
#pragma unroll
        for (int i = 0; i < 4; ++i) {
            f32x4 v = acc[i][j];
#pragma unroll
            for (int e = 0; e < 4; ++e) {
                const int m = blockM + i * 16 + q * 4 + e;
                out[(size_t)m * 1024 + n] = v[e] + bv;
            }
        }
    }
}

// ---------------------------------------------------------------------------
// Attention phase helpers (transposed-S, 8 waves x 16 q-rows each)
// ---------------------------------------------------------------------------
__device__ __forceinline__ void compute_S(const bf16_t* __restrict__ sK,
                                          const bf16x8 (&fQ)[2],
                                          f32x4 (&S)[4], int q, int r)
{
#pragma unroll
    for (int i = 0; i < 4; ++i) S[i] = (f32x4){0.f, 0.f, 0.f, 0.f};
#pragma unroll
    for (int ks = 0; ks < 2; ++ks) {
        bf16x8 fK[4];
#pragma unroll
        for (int i = 0; i < 4; ++i) {
            const int row = i * 16 + r;
            const int g = (ks * 4 + q) ^ (row & 7);
            fK[i] = *(const bf16x8*)&sK[row * 64 + g * 8];
        }
        __builtin_amdgcn_s_setprio(1);
#pragma unroll
        for (int i = 0; i < 4; ++i)
            S[i] = __builtin_amdgcn_mfma_f32_16x16x32_bf16(fK[i], fQ[ks], S[i], 0, 0, 0);
        __builtin_amdgcn_s_setprio(0);
    }
}

__device__ __forceinline__ void softmax_pw(f32x4 (&S)[4], bf16_t* __restrict__ sPt,
                                           float& l, int w, int q, int r)
{
    const int t = w * 16 + r;
    float part = 0.f;
#pragma unroll
    for (int i = 0; i < 4; ++i) {
        bf16x4 pk;
#pragma unroll
        for (int e = 0; e < 4; ++e) {
            const float p = __builtin_amdgcn_exp2f(S[i][e] * C_SCALE);
            part += p;
            pk[e] = (bf16_t)p;
        }
        const int sb = i * 16 + q * 4;
        const int g = (sb >> 3) ^ (t & 7);
        *(bf16x4*)&sPt[t * 64 + g * 8 + (sb & 7)] = pk;
    }
    l += part;
}

__device__ __forceinline__ void pv(const bf16_t* __restrict__ sPt,
                                   const bf16x8 (&fV)[4][2],
                                   f32x4 (&O)[4], int w, int q, int r)
{
#pragma unroll
    for (int ks = 0; ks < 2; ++ks) {
        const int m = w * 16 + r;
        const int g = (ks * 4 + q) ^ (m & 7);
        bf16x8 fP = *(const bf16x8*)&sPt[m * 64 + g * 8];
        __builtin_amdgcn_s_setprio(1);
#pragma unroll
        for (int j = 0; j < 4; ++j)
            O[j] = __builtin_amdgcn_mfma_f32_16x16x32_bf16(fP, fV[j][ks], O[j], 0, 0, 0);
        __builtin_amdgcn_s_setprio(0);
    }
}

// ---------------------------------------------------------------------------
// Differential flash attention. 512 threads = 8 waves x 16 q-rows -> 16
// waves/CU (4/SIMD) at 2 blocks/CU, double the old latency-hiding.
// LDS 57 KB: K1/K2 dbuf (32K) + sVt (8K) + single shared sPt (16K).
// Grid dim3(64, 8): x = bh (XCD-local K/V), y = qt (128 rows).
// ---------------------------------------------------------------------------
__global__ __launch_bounds__(512, 2)
void diff_attn_mfma(const bf16_t* __restrict__ q12, const bf16_t* __restrict__ k12v,
                    const float* __restrict__ lam, bf16_t* __restrict__ out,
                    float* __restrict__ stats)
{
    __shared__ bf16_t sK1[2][64 * 64];
    __shared__ bf16_t sK2[2][64 * 64];
    __shared__ bf16_t sVt[64 * 64];     // [d][s], swizzled
    __shared__ bf16_t sPt[128 * 64];    // [t][s], wave-private strips
    __shared__ float  sl1[128], sl2[128];
    __shared__ float  sred[16];

    const int tid = threadIdx.x;
    const int w = tid >> 6, lane = tid & 63;   // w in 0..7
    const int q = lane >> 4, r = lane & 15;
    const int bh = blockIdx.x, qt = blockIdx.y;
    const float lamv = lam[bh & (Hn - 1)];

    const size_t HT = (size_t)TKn * DHn;          // 65536
    const bf16_t* q1g = q12 + (size_t)bh * HT + (size_t)qt * 128 * DHn;
    const bf16_t* q2g = q1g + 64 * HT;
    const bf16_t* k1g = k12v + (size_t)bh * HT;
    const bf16_t* k2g = k1g + 64 * HT;
    const bf16_t* vg  = k1g + 128 * HT;

    // Q fragments in registers (B-operand layout), t = w*16 + r
    bf16x8 fQ1[2], fQ2[2];
    {
        const int t = w * 16 + r;
#pragma unroll
        for (int ks = 0; ks < 2; ++ks) {
            fQ1[ks] = *(const bf16x8*)(q1g + (size_t)t * 64 + ks * 32 + q * 8);
            fQ2[ks] = *(const bf16x8*)(q2g + (size_t)t * 64 + ks * 32 + q * 8);
        }
    }

    f32x4 O1[4], O2[4];
    float l1 = 0.f, l2 = 0.f;
#pragma unroll
    for (int j = 0; j < 4; ++j) { O1[j] = (f32x4){0.f,0.f,0.f,0.f}; O2[j] = (f32x4){0.f,0.f,0.f,0.f}; }

    // ---- prologue: stage K[0] (buf 0) and V[0] ----
    {
        const int row = tid >> 3;
        const int cg = (tid & 7) ^ (row & 7);
        GLDS16(k1g + row * 64 + cg * 8, &sK1[0][tid * 8]);
        GLDS16(k2g + row * 64 + cg * 8, &sK2[0][tid * 8]);
        const int s = tid & 63;
        bf16x8 v0 = *(const bf16x8*)(vg + (size_t)s * 64 + w * 8);
#pragma unroll
        for (int i = 0; i < 8; ++i) {
            const int d = w * 8 + i;
            sVt[d * 64 + (((s >> 3) ^ i) << 3) + (s & 7)] = v0[i];
        }
        __syncthreads();   // drains GLDS (vmcnt) + sVt writes
    }

    bf16x8 vr;
    for (int st = 0; st < TKn / 64; ++st) {
        const int cur = st & 1;
        // ---- prefetch next tile: K via GLDS dbuf, V into registers ----
        if (st < 15) {
            const int row = tid >> 3;
            const int cg = (tid & 7) ^ (row & 7);
            GLDS16(k1g + (size_t)(st + 1) * 4096 + row * 64 + cg * 8, &sK1[cur ^ 1][tid * 8]);
            GLDS16(k2g + (size_t)(st + 1) * 4096 + row * 64 + cg * 8, &sK2[cur ^ 1][tid * 8]);
            vr = *(const bf16x8*)(vg + (size_t)(st + 1) * 4096 + (size_t)(tid & 63) * 64 + w * 8);
        }

        // ---- compute on current tile ----
        bf16x8 fV[4][2];
#pragma unroll
        for (int j = 0; j < 4; ++j)
#pragma unroll
            for (int ks = 0; ks < 2; ++ks) {
                const int d = j * 16 + r;
                const int g = (ks * 4 + q) ^ (d & 7);
                fV[j][ks] = *(const bf16x8*)&sVt[d * 64 + g * 8];
            }
        {
            f32x4 S[4];
            compute_S(sK1[cur], fQ1, S, q, r);
            softmax_pw(S, sPt, l1, w, q, r);
            pv(sPt, fV, O1, w, q, r);
        }
        {
            f32x4 S[4];
            compute_S(sK2[cur], fQ2, S, q, r);
            softmax_pw(S, sPt, l2, w, q, r);
            pv(sPt, fV, O2, w, q, r);
        }

        __syncthreads();   // all waves done with sVt & sK[cur]; prefetches drained
        if (st < 15) {
            const int s = tid & 63;
#pragma unroll
            for (int i = 0; i < 8; ++i) {
                const int d = w * 8 + i;
                sVt[d * 64 + (((s >> 3) ^ i) << 3) + (s & 7)] = vr[i];
            }
            __syncthreads();   // sVt[st+1] visible
        }
    }

    // ---- l reduction across q-groups (k-chunks live in lane bits 4,5) ----
    {
        float v1 = l1;
        v1 += __shfl_xor(v1, 16); v1 += __shfl_xor(v1, 32);
        float v2 = l2;
        v2 += __shfl_xor(v2, 16); v2 += __shfl_xor(v2, 32);
        if (q == 0) { sl1[w * 16 + r] = v1; sl2[w * 16 + r] = v2; }
    }

    // ---- epilogue: out (bf16) + GN partial sums ----
    bf16_t* op = out + ((size_t)bh * TQn + (size_t)qt * 128) * DHn;
    float ssum = 0.f, ssq = 0.f;
#pragma unroll
    for (int e = 0; e < 4; ++e) {
        const int t = w * 16 + q * 4 + e;
        const float inv1 = 1.0f / sl1[t];
        const float inv2 = lamv / sl2[t];
#pragma unroll
        for (int j = 0; j < 4; ++j) {
            const float o = O1[j][e] * inv1 - O2[j][e] * inv2;
            op[(size_t)t * 64 + j * 16 + r] = (bf16_t)o;
            ssum += o;
            ssq += o * o;
        }
    }
#pragma unroll
    for (int d = 1; d < 64; d <<= 1) {
        ssum += __shfl_xor(ssum, d);
        ssq  += __shfl_xor(ssq, d);
    }
    if (lane == 0) { sred[w] = ssum; sred[8 + w] = ssq; }
    __syncthreads();
    if (tid == 0) {
        float a = 0.f, b = 0.f;
#pragma unroll
        for (int k = 0; k < 8; ++k) { a += sred[k]; b += sred[8 + k]; }
        stats[(bh << 3) + qt]       = a;
        stats[512 + (bh << 3) + qt] = b;
    }
}

// ---------------------------------------------------------------------------
// GroupNorm apply (mu/rstd from per-(bh,qt) partials) + transpose -> y bf16
// ---------------------------------------------------------------------------
__global__ __launch_bounds__(256)
void gn_apply(const bf16_t* __restrict__ attn, const float* __restrict__ stats,
              const float* __restrict__ gamma, const float* __restrict__ beta,
              bf16_t* __restrict__ y)
{
    const int f = blockIdx.x * 256 + threadIdx.x;   // 8-elem group, 0..524287
    const int d8 = (f & 7) << 3;
    const int t  = (f >> 3) & 1023;
    const int bh = f >> 13;
    const int h  = bh & 15;
    const int b  = bh >> 4;
    const float* p1 = stats + (bh << 3);
    const float* p2 = stats + 512 + (bh << 3);
    float s1 = 0.f, s2 = 0.f;
#pragma unroll
    for (int k = 0; k < 8; ++k) { s1 += p1[k]; s2 += p2[k]; }
    const float mu = s1 * (1.f / 65536.f);
    const float var = s2 * (1.f / 65536.f) - mu * mu;
    const float rstd = rsqrtf(var + EPSv);
    bf16x8 v = *(const bf16x8*)&attn[((size_t)bh << 16) + t * 64 + d8];
    const int c = h * 64 + d8;
    const float* gp = gamma + c;
    const float* bp = beta + c;
    bf16x8 o;
#pragma unroll
    for (int i = 0; i < 8; ++i)
        o[i] = (bf16_t)(((float)v[i] - mu) * rstd * gp[i] + bp[i]);
    *(bf16x8*)&y[((size_t)(b * 1024 + t)) * 1024 + c] = o;
}

// ---------------------------------------------------------------------------
extern "C" void kernel_launch(void* const* d_in, const int* in_sizes, int n_in,
                              void* d_out, int out_size, void* d_ws, size_t ws_size,
                              hipStream_t stream)
{
    const float* x    = (const float*)d_in[0];
    const float* enc  = (const float*)d_in[1];
    const float* Q1w  = (const float*)d_in[2];
    const float* Q1b  = (const float*)d_in[3];
    const float* Q2w  = (const float*)d_in[4];
    const float* Q2b  = (const float*)d_in[5];
    const float* K1w  = (const float*)d_in[6];
    const float* K1b  = (const float*)d_in[7];
    const float* K2w  = (const float*)d_in[8];
    const float* K2b  = (const float*)d_in[9];
    const float* Vw   = (const float*)d_in[10];
    const float* Vb   = (const float*)d_in[11];
    const float* lam  = (const float*)d_in[12];
    const float* gng  = (const float*)d_in[13];
    const float* gnb  = (const float*)d_in[14];
    const float* outw = (const float*)d_in[15];
    const float* outb = (const float*)d_in[16];
    float* out = (float*)d_out;

    // workspace layout (bf16 elems). Peak footprint 68 MB:
    // attnb/yb/stats alias regions that are dead after the projection GEMM.
    bf16_t* xb   = (bf16_t*)d_ws;            // 4,194,304   live k1..k2
    bf16_t* encb = xb   + 4194304;           // 4,194,304   live k1..k2
    bf16_t* wq   = encb + 4194304;           // 2,097,152   live k1..k2  [Q1w|Q2w]
    bf16_t* wkv  = wq   + 2097152;           // 3,145,728   live k1..k2  [K1w|K2w|Vw]
    bf16_t* wob  = wkv  + 3145728;           // 1,048,576   live k1..k5
    bf16_t* q12  = wob  + 1048576;           // 8,388,608   live k2..k3  [2][B][H][T][D]
    bf16_t* k12v = q12  + 8388608;           // 12,582,912  live k2..k3  [3][B][H][T][D]
    bf16_t* attnb= xb;                       // alias: written k3, read k4 (xb dead)
    bf16_t* yb   = encb;                     // alias: written k4, read k5 (encb dead)
    float*  stats= (float*)wq;               // alias: 1024 fp32, written k3, read k4 (wq dead)

    cvt_all<<<14336, 256, 0, stream>>>(x, enc, Q1w, Q2w, K1w, K2w, Vw, outw,
                                       xb, encb, wq, wkv, wob);

    gemm_proj<<<dim3(40, 32), 256, 0, stream>>>(xb, encb, wq, wkv,
                                                Q1b, Q2b, K1b, K2b, Vb, q12, k12v);

    diff_attn_mfma<<<dim3(64, 8), 512, 0, stream>>>(q12, k12v, lam, attnb, stats);

    gn_apply<<<2048, 256, 0, stream>>>(attnb, stats, gng, gnb, yb);

    gemm_out<<<512, 256, 0, stream>>>(yb, wob, outb, out);
}